// Round 8
// baseline (129.008 us; speedup 1.0000x reference)
//
#include <hip/hip_runtime.h>
#include <math.h>

// Problem constants (reference: N=250000, D=16, L=6, K=64, gamma=0.1)
#define NPOINTS 250000
#define LL 6
#define DD 16
#define KK 64
#define TPB 384            // 6 waves; wave w handles layer w for the block's points
#define PTS_PER_BLOCK 128  // smaller blocks -> 1954 blocks -> 45.8 waves/CU available
#define NTILES 8           // 8 MFMA tiles of 16 points each

// LDS layout (byte offsets into smem), phase-aliased:
//  Phase A: musc: column j of layer l at (l*64+j)*64, 24576 B
//  Phase B: sxu: point p at p*80 (80B: hi d0-7, hi d8-15, lo d0-7, lo d8-15, pad), 10240 B
//           smc: float at SMC_OFF + (l*128+p)*4, 3072 B   (both inside old musc region)
//  swv: 6 floats at SWV_OFF (never aliased)
#define SMC_OFF 10240
#define SWV_OFF 24576
#define LDS_BYTES (SWV_OFF + 32)

typedef __attribute__((ext_vector_type(8))) short bf16x8;
typedef __attribute__((ext_vector_type(4))) float f32x4;
typedef __attribute__((ext_vector_type(2))) float f32x2;

#if __has_builtin(__builtin_amdgcn_exp2f)
#define EXP2F(x) __builtin_amdgcn_exp2f(x)
#else
#define EXP2F(x) exp2f(x)
#endif
#if __has_builtin(__builtin_amdgcn_logf)
#define LOG2F(x) __builtin_amdgcn_logf(x)
#else
#define LOG2F(x) log2f(x)
#endif
#if __has_builtin(__builtin_amdgcn_sqrtf)
#define SQRTF(x) __builtin_amdgcn_sqrtf(x)
#else
#define SQRTF(x) sqrtf(x)
#endif

#define C_AA   (-14.426950408889634f)   // -10 * log2(e)
#define C_GLN2 (0.06931471805599453f)   // gamma * ln(2)

// acos poly folded with SQ_C = sqrt(5*log2e) = 2.6857914 so that
// u = SQ_C * acos(clip(x)) and t2 = -u^2 + aa = log2-arg of the exp term.
#define AC3 (-0.05030299f)
#define AC2 (0.19944957f)
#define AC1 (-0.56969503f)
#define AC0 (4.2186499f)
#define PI_HAT (8.4376625f)             // SQ_C * pi
#define CLIP_C (1.0f - 1e-7f)

__device__ __forceinline__ f32x2 s2(float v) { f32x2 r; r.x = v; r.y = v; return r; }

__device__ __forceinline__ ushort bf16_rne(float f) {
  unsigned u = __float_as_uint(f);
  unsigned r = u + 0x7FFFu + ((u >> 16) & 1u);
  return (ushort)(r >> 16);
}

// packed pair: exp2( -5*log2e*acos(clip(x))^2 + aa ), aa pre-splat
__device__ __forceinline__ f32x2 term2(f32x2 x, f32x2 aa) {
  // symmetric clip: ax = min(|x|, 1-1e-7); sign from raw x
  f32x2 ax = __builtin_elementwise_min(__builtin_elementwise_abs(x), s2(CLIP_C));
  f32x2 pp = __builtin_elementwise_fma(ax, s2(AC3), s2(AC2));   // v_pk_fma_f32
  pp = __builtin_elementwise_fma(pp, ax, s2(AC1));
  pp = __builtin_elementwise_fma(pp, ax, s2(AC0));
  f32x2 om = s2(1.0f) - ax;                                      // v_pk_add_f32
  f32x2 sq; sq.x = SQRTF(om.x); sq.y = SQRTF(om.y);
  f32x2 v = sq * pp;                                             // v_pk_mul_f32
  f32x2 u;
  u.x = (x.x < 0.0f) ? (PI_HAT - v.x) : v.x;
  u.y = (x.y < 0.0f) ? (PI_HAT - v.y) : v.y;
  f32x2 t2 = __builtin_elementwise_fma(u, -u, aa);               // v_pk_fma_f32
  f32x2 e; e.x = EXP2F(t2.x); e.y = EXP2F(t2.y);
  return e;
}

// DPP row-shift adds; after shr 1,2,4,8 lane 15 of each 16-row holds the sum.
#define DPP_ADD(S, CTRL)                                                     \
  {                                                                          \
    int _t = __builtin_amdgcn_update_dpp(0, __float_as_int(S), CTRL, 0xF,    \
                                         0xF, true);                         \
    S += __int_as_float(_t);                                                 \
  }
#define ROW_SHR1 0x111
#define ROW_SHR2 0x112
#define ROW_SHR4 0x114
#define ROW_SHR8 0x118

__global__ __launch_bounds__(TPB, 8) void
multiinf_kernel(const float* __restrict__ xs,
                const float* __restrict__ mus,    // [L, D, K]
                const float* __restrict__ alphas, // [L, K]
                const float* __restrict__ wsv,    // [L]
                float* __restrict__ out) {
  __shared__ __align__(16) char smem[LDS_BYTES];
  float* swv = (float*)(smem + SWV_OFF);
  float* smc = (float*)(smem + SMC_OFF);

  const int tid = threadIdx.x;
  const int w = tid >> 6;            // wave = layer
  const int lane = tid & 63;
  const int c = lane & 15;           // MFMA col (comp-in-block / point-in-tile)
  const int q = lane >> 4;           // quad
  const int h = q & 1;               // dim half
  const int pbase = blockIdx.x * PTS_PER_BLOCK;

  // Prefetch this thread's x point (threads 0..127) to overlap with phase A
  float xv[DD];
  {
    int gidx = pbase + tid;
    if (tid < PTS_PER_BLOCK && gidx < NPOINTS) {
      const float4* x4 = (const float4*)(xs + (size_t)gidx * DD);
#pragma unroll
      for (int j = 0; j < 4; ++j) {
        float4 a = x4[j];
        xv[j * 4 + 0] = a.x; xv[j * 4 + 1] = a.y;
        xv[j * 4 + 2] = a.z; xv[j * 4 + 3] = a.w;
      }
    } else {
#pragma unroll
      for (int d = 0; d < DD; ++d) xv[d] = 0.0f;
    }
  }

  // ---- Phase A: wave w normalizes column `lane` of layer w, splits bf16 hi/lo,
  //      writes 64B column record into musc scratch ----
  {
    const float* colp = mus + w * (DD * KK) + lane;   // stride KK over d (coalesced per d)
    float v[DD];
    float ss = 0.0f;
#pragma unroll
    for (int d = 0; d < DD; ++d) { v[d] = colp[d * KK]; ss = fmaf(v[d], v[d], ss); }
    float inv = 1.0f / sqrtf(ss);
    unsigned hw[8], lw[8];
#pragma unroll
    for (int i = 0; i < 8; ++i) {
      float a0 = v[2 * i] * inv;
      float a1 = v[2 * i + 1] * inv;
      ushort h0 = bf16_rne(a0), h1 = bf16_rne(a1);
      float hf0 = __uint_as_float((unsigned)h0 << 16);
      float hf1 = __uint_as_float((unsigned)h1 << 16);
      ushort l0 = bf16_rne(a0 - hf0), l1 = bf16_rne(a1 - hf1);
      hw[i] = (unsigned)h0 | ((unsigned)h1 << 16);
      lw[i] = (unsigned)l0 | ((unsigned)l1 << 16);
    }
    uint4* colq = (uint4*)(smem + (w * 64 + lane) * 64);
    colq[0] = make_uint4(hw[0], hw[1], hw[2], hw[3]);
    colq[1] = make_uint4(hw[4], hw[5], hw[6], hw[7]);
    colq[2] = make_uint4(lw[0], lw[1], lw[2], lw[3]);
    colq[3] = make_uint4(lw[4], lw[5], lw[6], lw[7]);
  }
  float av = C_AA * alphas[w * 64 + lane];   // alpha of column `lane`
  if (tid < LL) { float t = wsv[tid]; swv[tid] = expf(-t * t); }
  __syncthreads();

  // ---- Read B fragments into registers (resident for the whole main loop) ----
  bf16x8 Bh[4], Bl[4];
  f32x2 aa2[4];
#pragma unroll
  for (int cb = 0; cb < 4; ++cb) {
    const char* base = smem + (w * 64 + cb * 16 + c) * 64 + h * 16;
    Bh[cb] = *(const bf16x8*)(base);
    Bl[cb] = *(const bf16x8*)(base + 32);
    aa2[cb] = s2(__shfl(av, cb * 16 + c, 64));
  }
  __syncthreads();   // all frag reads done; musc region now reusable

  // ---- Phase B: stage x A-fragments (bf16 hi/lo) into sxu ----
  if (tid < PTS_PER_BLOCK) {
    unsigned hw[8], lw[8];
#pragma unroll
    for (int i = 0; i < 8; ++i) {
      ushort h0 = bf16_rne(xv[2 * i]);
      ushort h1 = bf16_rne(xv[2 * i + 1]);
      float hf0 = __uint_as_float((unsigned)h0 << 16);
      float hf1 = __uint_as_float((unsigned)h1 << 16);
      ushort l0 = bf16_rne(xv[2 * i] - hf0);
      ushort l1 = bf16_rne(xv[2 * i + 1] - hf1);
      hw[i] = (unsigned)h0 | ((unsigned)h1 << 16);
      lw[i] = (unsigned)l0 | ((unsigned)l1 << 16);
    }
    uint4* pq = (uint4*)(smem + tid * 80);
    pq[0] = make_uint4(hw[0], hw[1], hw[2], hw[3]);
    pq[1] = make_uint4(hw[4], hw[5], hw[6], hw[7]);
    pq[2] = make_uint4(lw[0], lw[1], lw[2], lw[3]);
    pq[3] = make_uint4(lw[4], lw[5], lw[6], lw[7]);
  }
  __syncthreads();

  // ---- Main loop: 8 tiles of 16 points, A-fragment software-prefetched ----
  float* smcw = smc + w * PTS_PER_BLOCK;
  bf16x8 A = *(const bf16x8*)(smem + (0 * 16 + c) * 80 + q * 16);
  for (int t = 0; t < NTILES; ++t) {
    // issue next tile's A read now; the term math below covers the latency
    bf16x8 An = *(const bf16x8*)(smem + ((((t + 1) & (NTILES - 1)) * 16) + c) * 80 + q * 16);

    f32x2 S01 = s2(0.0f), S23 = s2(0.0f);
#pragma unroll
    for (int cb = 0; cb < 4; ++cb) {
      f32x4 acc = {0.0f, 0.0f, 0.0f, 0.0f};
      acc = __builtin_amdgcn_mfma_f32_16x16x32_bf16(A, Bh[cb], acc, 0, 0, 0);
      acc = __builtin_amdgcn_mfma_f32_16x16x32_bf16(A, Bl[cb], acc, 0, 0, 0);
      f32x2 a01; a01.x = acc[0]; a01.y = acc[1];
      f32x2 a23; a23.x = acc[2]; a23.y = acc[3];
      S01 += term2(a01, aa2[cb]);   // v_pk_add_f32
      S23 += term2(a23, aa2[cb]);
    }
    float S0 = S01.x, S1 = S01.y, S2 = S23.x, S3 = S23.y;
    // sum over the 16 comp-lanes: DPP row scan, total lands in lane 15 of row
    DPP_ADD(S0, ROW_SHR1) DPP_ADD(S1, ROW_SHR1) DPP_ADD(S2, ROW_SHR1) DPP_ADD(S3, ROW_SHR1)
    DPP_ADD(S0, ROW_SHR2) DPP_ADD(S1, ROW_SHR2) DPP_ADD(S2, ROW_SHR2) DPP_ADD(S3, ROW_SHR2)
    DPP_ADD(S0, ROW_SHR4) DPP_ADD(S1, ROW_SHR4) DPP_ADD(S2, ROW_SHR4) DPP_ADD(S3, ROW_SHR4)
    DPP_ADD(S0, ROW_SHR8) DPP_ADD(S1, ROW_SHR8) DPP_ADD(S2, ROW_SHR8) DPP_ADD(S3, ROW_SHR8)

    if (c == 15) {   // rows q*4+r; store raw sums, log applied in epilogue
      smcw[t * 16 + q * 4 + 0] = S0;
      smcw[t * 16 + q * 4 + 1] = S1;
      smcw[t * 16 + q * 4 + 2] = S2;
      smcw[t * 16 + q * 4 + 3] = S3;
    }
    A = An;
  }
  __syncthreads();

  // ---- Epilogue: recurrence + smooth-min, one thread per point ----
  if (tid < PTS_PER_BLOCK) {
    float F = 0.0f;
#pragma unroll
    for (int l = 0; l < LL; ++l) {
      float wv = swv[l];
      float mc = C_GLN2 * LOG2F(smc[l * PTS_PER_BLOCK + tid]);  // gamma*ln(S)
      F = fmaf(wv, fmaxf(F, 0.0f), (1.0f - wv) * mc);
    }
    int idx = pbase + tid;
    if (idx < NPOINTS) {
      float e = EXP2F(F * C_AA);              // exp(-F/0.1)
      out[idx] = C_GLN2 * LOG2F(1.0f + e);    // 0.1 * ln(1 + e)
    }
  }
}

extern "C" void kernel_launch(void* const* d_in, const int* in_sizes, int n_in,
                              void* d_out, int out_size, void* d_ws, size_t ws_size,
                              hipStream_t stream) {
  const float* xs = (const float*)d_in[0];     // [N, D]
  const float* mus = (const float*)d_in[1];    // [L, D, K]
  const float* alphas = (const float*)d_in[2]; // [L, K]
  const float* wsv = (const float*)d_in[3];    // [L]
  float* out = (float*)d_out;
  (void)d_ws; (void)ws_size;

  const int blocks = (NPOINTS + PTS_PER_BLOCK - 1) / PTS_PER_BLOCK;  // 1954
  multiinf_kernel<<<blocks, TPB, 0, stream>>>(xs, mus, alphas, wsv, out);
}

// Round 9
// 116.871 us; speedup vs baseline: 1.1038x; 1.1038x over previous
//
#include <hip/hip_runtime.h>
#include <math.h>

// Problem constants (reference: N=250000, D=16, L=6, K=64, gamma=0.1)
#define NPOINTS 250000
#define LL 6
#define DD 16
#define KK 64
#define TPB 384            // 6 waves; wave w handles layer w for the block's 256 points
#define PTS_PER_BLOCK 256
#define NTILES 16          // 16 MFMA tiles of 16 points each

// LDS layout (byte offsets into smem), phase-aliased:
//  Phase A: musc: column j of layer l at (l*64+j)*64, 24576 B
//           record: [muhi d0-7 16B][muhi d8-15][mulo d0-7][mulo d8-15]
//  Phase B: sxu: point p at p*80 (80B: xhi d0-7, xhi d8-15, xlo d0-7, xlo d8-15, pad), 20480 B
//           smc: float at SMC_OFF + (l*256+p)*4, 6144 B
//  swv: 6 floats at SWV_OFF (never aliased)
#define SMC_OFF 20480
#define SWV_OFF 26624
#define LDS_BYTES (SWV_OFF + 32)

typedef __attribute__((ext_vector_type(8))) short bf16x8;
typedef __attribute__((ext_vector_type(4))) float f32x4;
typedef __attribute__((ext_vector_type(2))) float f32x2;

#if __has_builtin(__builtin_amdgcn_exp2f)
#define EXP2F(x) __builtin_amdgcn_exp2f(x)
#else
#define EXP2F(x) exp2f(x)
#endif
#if __has_builtin(__builtin_amdgcn_logf)
#define LOG2F(x) __builtin_amdgcn_logf(x)
#else
#define LOG2F(x) log2f(x)
#endif
#if __has_builtin(__builtin_amdgcn_sqrtf)
#define SQRTF(x) __builtin_amdgcn_sqrtf(x)
#else
#define SQRTF(x) sqrtf(x)
#endif

#define C_AA   (-14.426950408889634f)   // -10 * log2(e)
#define C_GLN2 (0.06931471805599453f)   // gamma * ln(2)

// acos poly folded with SQ_C = sqrt(5*log2e) = 2.6857914 so that
// u = SQ_C * acos(clip(x)) and t2 = -u^2 + aa = log2-arg of the exp term.
#define AC3 (-0.05030299f)
#define AC2 (0.19944957f)
#define AC1 (-0.56969503f)
#define AC0 (4.2186499f)
#define PI_HAT (8.4376625f)             // SQ_C * pi
#define CLIP_C (1.0f - 1e-7f)

__device__ __forceinline__ f32x2 s2(float v) { f32x2 r; r.x = v; r.y = v; return r; }

__device__ __forceinline__ ushort bf16_rne(float f) {
  unsigned u = __float_as_uint(f);
  unsigned r = u + 0x7FFFu + ((u >> 16) & 1u);
  return (ushort)(r >> 16);
}

// packed pair: exp2( -5*log2e*acos(clip(x))^2 + aa ), aa pre-splat
__device__ __forceinline__ f32x2 term2(f32x2 x, f32x2 aa) {
  f32x2 ax = __builtin_elementwise_min(__builtin_elementwise_abs(x), s2(CLIP_C));
  f32x2 pp = __builtin_elementwise_fma(ax, s2(AC3), s2(AC2));   // v_pk_fma_f32
  pp = __builtin_elementwise_fma(pp, ax, s2(AC1));
  pp = __builtin_elementwise_fma(pp, ax, s2(AC0));
  f32x2 om = s2(1.0f) - ax;                                      // v_pk_add_f32
  f32x2 sq; sq.x = SQRTF(om.x); sq.y = SQRTF(om.y);
  f32x2 v = sq * pp;                                             // v_pk_mul_f32
  f32x2 u;
  u.x = (x.x < 0.0f) ? (PI_HAT - v.x) : v.x;
  u.y = (x.y < 0.0f) ? (PI_HAT - v.y) : v.y;
  f32x2 t2 = __builtin_elementwise_fma(u, -u, aa);               // v_pk_fma_f32
  f32x2 e; e.x = EXP2F(t2.x); e.y = EXP2F(t2.y);
  return e;
}

__global__ __launch_bounds__(TPB, 5) void
multiinf_kernel(const float* __restrict__ xs,
                const float* __restrict__ mus,    // [L, D, K]
                const float* __restrict__ alphas, // [L, K]
                const float* __restrict__ wsv,    // [L]
                float* __restrict__ out) {
  __shared__ __align__(16) char smem[LDS_BYTES];
  float* swv = (float*)(smem + SWV_OFF);
  float* smc = (float*)(smem + SMC_OFF);

  const int tid = threadIdx.x;
  const int w = tid >> 6;            // wave = layer
  const int lane = tid & 63;
  const int c = lane & 15;           // MFMA col: POINT-in-tile (and comp-in-cb for A read)
  const int q = lane >> 4;           // quad: C rows q*4..q*4+3 = comps; A/B k-slice
  const int h = q & 1;               // dim half for B (x) reads
  const int pbase = blockIdx.x * PTS_PER_BLOCK;

  // Prefetch this thread's x point (threads 0..255) to overlap with phase A
  float xv[DD];
  {
    int gidx = pbase + tid;
    if (tid < PTS_PER_BLOCK && gidx < NPOINTS) {
      const float4* x4 = (const float4*)(xs + (size_t)gidx * DD);
#pragma unroll
      for (int j = 0; j < 4; ++j) {
        float4 a = x4[j];
        xv[j * 4 + 0] = a.x; xv[j * 4 + 1] = a.y;
        xv[j * 4 + 2] = a.z; xv[j * 4 + 3] = a.w;
      }
    } else {
#pragma unroll
      for (int d = 0; d < DD; ++d) xv[d] = 0.0f;
    }
  }

  // ---- Phase A: wave w normalizes column `lane` of layer w, splits bf16 hi/lo,
  //      writes 64B column record into musc scratch ----
  {
    const float* colp = mus + w * (DD * KK) + lane;   // stride KK over d (coalesced per d)
    float v[DD];
    float ss = 0.0f;
#pragma unroll
    for (int d = 0; d < DD; ++d) { v[d] = colp[d * KK]; ss = fmaf(v[d], v[d], ss); }
    float inv = 1.0f / sqrtf(ss);
    unsigned hw[8], lw[8];
#pragma unroll
    for (int i = 0; i < 8; ++i) {
      float a0 = v[2 * i] * inv;
      float a1 = v[2 * i + 1] * inv;
      ushort h0 = bf16_rne(a0), h1 = bf16_rne(a1);
      float hf0 = __uint_as_float((unsigned)h0 << 16);
      float hf1 = __uint_as_float((unsigned)h1 << 16);
      ushort l0 = bf16_rne(a0 - hf0), l1 = bf16_rne(a1 - hf1);
      hw[i] = (unsigned)h0 | ((unsigned)h1 << 16);
      lw[i] = (unsigned)l0 | ((unsigned)l1 << 16);
    }
    uint4* colq = (uint4*)(smem + (w * 64 + lane) * 64);
    colq[0] = make_uint4(hw[0], hw[1], hw[2], hw[3]);
    colq[1] = make_uint4(hw[4], hw[5], hw[6], hw[7]);
    colq[2] = make_uint4(lw[0], lw[1], lw[2], lw[3]);
    colq[3] = make_uint4(lw[4], lw[5], lw[6], lw[7]);
  }
  float av = C_AA * alphas[w * 64 + lane];   // alpha of column `lane`
  if (tid < LL) { float t = wsv[tid]; swv[tid] = expf(-t * t); }
  __syncthreads();

  // ---- Read A fragments (mu, loop-invariant) into registers ----
  // A[m=comp, k]: m = c (comp-in-cb), k = q*8+j over [muhi(16); mulo(16)]
  // -> 16B at column record offset q*16 (record layout matches exactly).
  bf16x8 Am[4];
  f32x2 aaL[4], aaH[4];   // aa for comps q*4+{0,1} and q*4+{2,3} per cb
#pragma unroll
  for (int cb = 0; cb < 4; ++cb) {
    Am[cb] = *(const bf16x8*)(smem + (w * 64 + cb * 16 + c) * 64 + q * 16);
    int base = cb * 16 + q * 4;
    aaL[cb].x = __shfl(av, base + 0, 64);
    aaL[cb].y = __shfl(av, base + 1, 64);
    aaH[cb].x = __shfl(av, base + 2, 64);
    aaH[cb].y = __shfl(av, base + 3, 64);
  }
  __syncthreads();   // all mu reads done; musc region now reusable

  // ---- Phase B: stage x (bf16 hi/lo) into sxu ----
  if (tid < PTS_PER_BLOCK) {
    unsigned hw[8], lw[8];
#pragma unroll
    for (int i = 0; i < 8; ++i) {
      ushort h0 = bf16_rne(xv[2 * i]);
      ushort h1 = bf16_rne(xv[2 * i + 1]);
      float hf0 = __uint_as_float((unsigned)h0 << 16);
      float hf1 = __uint_as_float((unsigned)h1 << 16);
      ushort l0 = bf16_rne(xv[2 * i] - hf0);
      ushort l1 = bf16_rne(xv[2 * i + 1] - hf1);
      hw[i] = (unsigned)h0 | ((unsigned)h1 << 16);
      lw[i] = (unsigned)l0 | ((unsigned)l1 << 16);
    }
    uint4* pq = (uint4*)(smem + tid * 80);
    pq[0] = make_uint4(hw[0], hw[1], hw[2], hw[3]);
    pq[1] = make_uint4(hw[4], hw[5], hw[6], hw[7]);
    pq[2] = make_uint4(lw[0], lw[1], lw[2], lw[3]);
    pq[3] = make_uint4(lw[4], lw[5], lw[6], lw[7]);
  }
  __syncthreads();

  // ---- Main loop: 16 tiles of 16 points; lane owns point c of each tile ----
  // B[k, n]: n = c (point), k-slice by q: B1 = [xhi; xhi] dup (read h*16),
  // B2 = [xlo; xlo] dup (read 32 + h*16). Reused across all 4 cb.
  float* smcw = smc + w * PTS_PER_BLOCK;
  bf16x8 Bh = *(const bf16x8*)(smem + (0 * 16 + c) * 80 + h * 16);
  bf16x8 Bl = *(const bf16x8*)(smem + (0 * 16 + c) * 80 + 32 + h * 16);
  for (int t = 0; t < NTILES; ++t) {
    int tn = ((t + 1) & 15) * 16 + c;
    bf16x8 Bhn = *(const bf16x8*)(smem + tn * 80 + h * 16);
    bf16x8 Bln = *(const bf16x8*)(smem + tn * 80 + 32 + h * 16);

    f32x2 S01 = s2(0.0f), S23 = s2(0.0f);
#pragma unroll
    for (int cb = 0; cb < 4; ++cb) {
      f32x4 acc = {0.0f, 0.0f, 0.0f, 0.0f};
      // acc = (muhi+mulo) . (xhi+xlo) for comps q*4+r (rows), point c (col)
      acc = __builtin_amdgcn_mfma_f32_16x16x32_bf16(Am[cb], Bh, acc, 0, 0, 0);
      acc = __builtin_amdgcn_mfma_f32_16x16x32_bf16(Am[cb], Bl, acc, 0, 0, 0);
      f32x2 a01; a01.x = acc[0]; a01.y = acc[1];
      f32x2 a23; a23.x = acc[2]; a23.y = acc[3];
      S01 += term2(a01, aaL[cb]);   // v_pk_add_f32
      S23 += term2(a23, aaH[cb]);
    }
    // in-lane fold: sum of this lane's 16 comps for point c
    f32x2 Sf = S01 + S23;
    float St = Sf.x + Sf.y;
    // cross-quad fold: lanes c, c+16, c+32, c+48 hold disjoint comp groups
    St += __shfl_xor(St, 16, 64);
    St += __shfl_xor(St, 32, 64);

    if (lane < 16) smcw[t * 16 + c] = St;   // raw sum; log applied in epilogue
    Bh = Bhn;
    Bl = Bln;
  }
  __syncthreads();

  // ---- Epilogue: recurrence + smooth-min, one thread per point ----
  if (tid < PTS_PER_BLOCK) {
    float F = 0.0f;
#pragma unroll
    for (int l = 0; l < LL; ++l) {
      float wv = swv[l];
      float mc = C_GLN2 * LOG2F(smc[l * PTS_PER_BLOCK + tid]);  // gamma*ln(S)
      F = fmaf(wv, fmaxf(F, 0.0f), (1.0f - wv) * mc);
    }
    int idx = pbase + tid;
    if (idx < NPOINTS) {
      float e = EXP2F(F * C_AA);              // exp(-F/0.1)
      out[idx] = C_GLN2 * LOG2F(1.0f + e);    // 0.1 * ln(1 + e)
    }
  }
}

extern "C" void kernel_launch(void* const* d_in, const int* in_sizes, int n_in,
                              void* d_out, int out_size, void* d_ws, size_t ws_size,
                              hipStream_t stream) {
  const float* xs = (const float*)d_in[0];     // [N, D]
  const float* mus = (const float*)d_in[1];    // [L, D, K]
  const float* alphas = (const float*)d_in[2]; // [L, K]
  const float* wsv = (const float*)d_in[3];    // [L]
  float* out = (float*)d_out;
  (void)d_ws; (void)ws_size;

  const int blocks = (NPOINTS + PTS_PER_BLOCK - 1) / PTS_PER_BLOCK;  // 977
  multiinf_kernel<<<blocks, TPB, 0, stream>>>(xs, mus, alphas, wsv, out);
}

// Round 10
// 105.467 us; speedup vs baseline: 1.2232x; 1.1081x over previous
//
#include <hip/hip_runtime.h>
#include <math.h>

// Problem constants (reference: N=250000, D=16, L=6, K=64, gamma=0.1)
#define NPOINTS 250000
#define LL 6
#define DD 16
#define KK 64
#define TPB 384            // 6 waves; wave w handles layer w for the block's 256 points
#define PTS_PER_BLOCK 256
#define NTILES 16          // 16 MFMA tiles of 16 points each

// LDS layout (byte offsets into smem), phase-aliased:
//  Phase A: musc: column j of layer l at (l*64+j)*64, 24576 B
//  Phase B: sxu: point p at p*80, 20480 B; smc at SMC_OFF, 6144 B
//  swv: 6 floats at SWV_OFF (never aliased)
#define SMC_OFF 20480
#define SWV_OFF 26624
#define LDS_BYTES (SWV_OFF + 32)

typedef __attribute__((ext_vector_type(8))) short bf16x8;
typedef __attribute__((ext_vector_type(4))) float f32x4;
typedef __attribute__((ext_vector_type(2))) float f32x2;

#if __has_builtin(__builtin_amdgcn_exp2f)
#define EXP2F(x) __builtin_amdgcn_exp2f(x)
#else
#define EXP2F(x) exp2f(x)
#endif
#if __has_builtin(__builtin_amdgcn_logf)
#define LOG2F(x) __builtin_amdgcn_logf(x)
#else
#define LOG2F(x) log2f(x)
#endif

#define C_AA   (-14.426950408889634f)   // -10 * log2(e)
#define C_GLN2 (0.06931471805599453f)   // gamma * ln(2)

// Half-angle sqrt-free distance:
//   acos(x) = 2*asin(s), s = sqrt(z), z = (1-x)/2
//   u = SQ_C*acos(x) = s * Phat(z),  Phat = 2*SQ_C*asin_series(s)/s  (poly in z!)
//   u^2 = z * Phat(z)^2  ->  t2 = aa - (z*Phat)*Phat      [no sqrt anywhere]
// Phat coeffs: 2*sqrt(5*log2e) * asin Maclaurin coeffs (exact series values).
#define B0 5.3715828f
#define B1 0.89526380f
#define B2 0.40286871f
#define B3 0.23980260f
#define B4 0.16319928f
#define B5 0.12017370f
#define B6 0.09321181f
#define B7 0.07501322f
#define B8 0.06205089f

__device__ __forceinline__ f32x2 s2(float v) { f32x2 r; r.x = v; r.y = v; return r; }

__device__ __forceinline__ ushort bf16_rne(float f) {
  unsigned u = __float_as_uint(f);
  unsigned r = u + 0x7FFFu + ((u >> 16) & 1u);
  return (ushort)(r >> 16);
}

// packed pair: exp2( -5*log2e*acos(x)^2 + aa ), branchless & sqrt-free
__device__ __forceinline__ f32x2 term2(f32x2 x, f32x2 aa) {
  f32x2 z = __builtin_elementwise_fma(x, s2(-0.5f), s2(0.5f));  // (1-x)/2
  f32x2 P = s2(B8);
  P = __builtin_elementwise_fma(P, z, s2(B7));
  P = __builtin_elementwise_fma(P, z, s2(B6));
  P = __builtin_elementwise_fma(P, z, s2(B5));
  P = __builtin_elementwise_fma(P, z, s2(B4));
  P = __builtin_elementwise_fma(P, z, s2(B3));
  P = __builtin_elementwise_fma(P, z, s2(B2));
  P = __builtin_elementwise_fma(P, z, s2(B1));
  P = __builtin_elementwise_fma(P, z, s2(B0));
  f32x2 m = z * P;                                    // z*Phat
  f32x2 t2 = __builtin_elementwise_fma(m, -P, aa);    // aa - z*Phat^2
  f32x2 e; e.x = EXP2F(t2.x); e.y = EXP2F(t2.y);
  return e;
}

__global__ __launch_bounds__(TPB, 5) void
multiinf_kernel(const float* __restrict__ xs,
                const float* __restrict__ mus,    // [L, D, K]
                const float* __restrict__ alphas, // [L, K]
                const float* __restrict__ wsv,    // [L]
                float* __restrict__ out) {
  __shared__ __align__(16) char smem[LDS_BYTES];
  float* swv = (float*)(smem + SWV_OFF);
  float* smc = (float*)(smem + SMC_OFF);

  const int tid = threadIdx.x;
  const int w = tid >> 6;            // wave = layer
  const int lane = tid & 63;
  const int c = lane & 15;           // MFMA col: point-in-tile (comp-in-cb for A read)
  const int q = lane >> 4;           // quad
  const int h = q & 1;               // dim half for B (x) reads
  const int pbase = blockIdx.x * PTS_PER_BLOCK;

  // Prefetch this thread's x point (threads 0..255) to overlap with phase A
  float xv[DD];
  {
    int gidx = pbase + tid;
    if (tid < PTS_PER_BLOCK && gidx < NPOINTS) {
      const float4* x4 = (const float4*)(xs + (size_t)gidx * DD);
#pragma unroll
      for (int j = 0; j < 4; ++j) {
        float4 a = x4[j];
        xv[j * 4 + 0] = a.x; xv[j * 4 + 1] = a.y;
        xv[j * 4 + 2] = a.z; xv[j * 4 + 3] = a.w;
      }
    } else {
#pragma unroll
      for (int d = 0; d < DD; ++d) xv[d] = 0.0f;
    }
  }

  // ---- Phase A: wave w normalizes column `lane` of layer w, splits bf16 hi/lo ----
  {
    const float* colp = mus + w * (DD * KK) + lane;   // stride KK over d
    float v[DD];
    float ss = 0.0f;
#pragma unroll
    for (int d = 0; d < DD; ++d) { v[d] = colp[d * KK]; ss = fmaf(v[d], v[d], ss); }
    float inv = 1.0f / sqrtf(ss);
    unsigned hw[8], lw[8];
#pragma unroll
    for (int i = 0; i < 8; ++i) {
      float a0 = v[2 * i] * inv;
      float a1 = v[2 * i + 1] * inv;
      ushort h0 = bf16_rne(a0), h1 = bf16_rne(a1);
      float hf0 = __uint_as_float((unsigned)h0 << 16);
      float hf1 = __uint_as_float((unsigned)h1 << 16);
      ushort l0 = bf16_rne(a0 - hf0), l1 = bf16_rne(a1 - hf1);
      hw[i] = (unsigned)h0 | ((unsigned)h1 << 16);
      lw[i] = (unsigned)l0 | ((unsigned)l1 << 16);
    }
    uint4* colq = (uint4*)(smem + (w * 64 + lane) * 64);
    colq[0] = make_uint4(hw[0], hw[1], hw[2], hw[3]);
    colq[1] = make_uint4(hw[4], hw[5], hw[6], hw[7]);
    colq[2] = make_uint4(lw[0], lw[1], lw[2], lw[3]);
    colq[3] = make_uint4(lw[4], lw[5], lw[6], lw[7]);
  }
  float av = C_AA * alphas[w * 64 + lane];   // alpha of column `lane`
  if (tid < LL) { float t = wsv[tid]; swv[tid] = expf(-t * t); }
  __syncthreads();

  // ---- Read A fragments (mu, loop-invariant) into registers ----
  bf16x8 Am[4];
  f32x2 aaL[4], aaH[4];   // aa for comps q*4+{0,1} and q*4+{2,3} per cb
#pragma unroll
  for (int cb = 0; cb < 4; ++cb) {
    Am[cb] = *(const bf16x8*)(smem + (w * 64 + cb * 16 + c) * 64 + q * 16);
    int base = cb * 16 + q * 4;
    aaL[cb].x = __shfl(av, base + 0, 64);
    aaL[cb].y = __shfl(av, base + 1, 64);
    aaH[cb].x = __shfl(av, base + 2, 64);
    aaH[cb].y = __shfl(av, base + 3, 64);
  }
  __syncthreads();   // all mu reads done; musc region now reusable

  // ---- Phase B: stage x (bf16 hi/lo) into sxu ----
  if (tid < PTS_PER_BLOCK) {
    unsigned hw[8], lw[8];
#pragma unroll
    for (int i = 0; i < 8; ++i) {
      ushort h0 = bf16_rne(xv[2 * i]);
      ushort h1 = bf16_rne(xv[2 * i + 1]);
      float hf0 = __uint_as_float((unsigned)h0 << 16);
      float hf1 = __uint_as_float((unsigned)h1 << 16);
      ushort l0 = bf16_rne(xv[2 * i] - hf0);
      ushort l1 = bf16_rne(xv[2 * i + 1] - hf1);
      hw[i] = (unsigned)h0 | ((unsigned)h1 << 16);
      lw[i] = (unsigned)l0 | ((unsigned)l1 << 16);
    }
    uint4* pq = (uint4*)(smem + tid * 80);
    pq[0] = make_uint4(hw[0], hw[1], hw[2], hw[3]);
    pq[1] = make_uint4(hw[4], hw[5], hw[6], hw[7]);
    pq[2] = make_uint4(lw[0], lw[1], lw[2], lw[3]);
    pq[3] = make_uint4(lw[4], lw[5], lw[6], lw[7]);
  }
  __syncthreads();

  // ---- Main loop: 16 tiles of 16 points; lane owns point c of each tile ----
  float* smcw = smc + w * PTS_PER_BLOCK;
  bf16x8 Bh = *(const bf16x8*)(smem + (0 * 16 + c) * 80 + h * 16);
  bf16x8 Bl = *(const bf16x8*)(smem + (0 * 16 + c) * 80 + 32 + h * 16);
  for (int t = 0; t < NTILES; ++t) {
    int tn = ((t + 1) & 15) * 16 + c;
    bf16x8 Bhn = *(const bf16x8*)(smem + tn * 80 + h * 16);
    bf16x8 Bln = *(const bf16x8*)(smem + tn * 80 + 32 + h * 16);

    f32x2 S01 = s2(0.0f), S23 = s2(0.0f);
#pragma unroll
    for (int cb = 0; cb < 4; ++cb) {
      f32x4 acc = {0.0f, 0.0f, 0.0f, 0.0f};
      acc = __builtin_amdgcn_mfma_f32_16x16x32_bf16(Am[cb], Bh, acc, 0, 0, 0);
      acc = __builtin_amdgcn_mfma_f32_16x16x32_bf16(Am[cb], Bl, acc, 0, 0, 0);
      f32x2 a01; a01.x = acc[0]; a01.y = acc[1];
      f32x2 a23; a23.x = acc[2]; a23.y = acc[3];
      S01 += term2(a01, aaL[cb]);
      S23 += term2(a23, aaH[cb]);
    }
    f32x2 Sf = S01 + S23;
    float St = Sf.x + Sf.y;
    St += __shfl_xor(St, 16, 64);
    St += __shfl_xor(St, 32, 64);

    if (lane < 16) smcw[t * 16 + c] = St;   // raw sum; log applied in epilogue
    Bh = Bhn;
    Bl = Bln;
  }
  __syncthreads();

  // ---- Epilogue: recurrence + smooth-min, one thread per point ----
  if (tid < PTS_PER_BLOCK) {
    float F = 0.0f;
#pragma unroll
    for (int l = 0; l < LL; ++l) {
      float wv = swv[l];
      float mc = C_GLN2 * LOG2F(smc[l * PTS_PER_BLOCK + tid]);  // gamma*ln(S)
      F = fmaf(wv, fmaxf(F, 0.0f), (1.0f - wv) * mc);
    }
    int idx = pbase + tid;
    if (idx < NPOINTS) {
      float e = EXP2F(F * C_AA);              // exp(-F/0.1)
      out[idx] = C_GLN2 * LOG2F(1.0f + e);    // 0.1 * ln(1 + e)
    }
  }
}

extern "C" void kernel_launch(void* const* d_in, const int* in_sizes, int n_in,
                              void* d_out, int out_size, void* d_ws, size_t ws_size,
                              hipStream_t stream) {
  const float* xs = (const float*)d_in[0];     // [N, D]
  const float* mus = (const float*)d_in[1];    // [L, D, K]
  const float* alphas = (const float*)d_in[2]; // [L, K]
  const float* wsv = (const float*)d_in[3];    // [L]
  float* out = (float*)d_out;
  (void)d_ws; (void)ws_size;

  const int blocks = (NPOINTS + PTS_PER_BLOCK - 1) / PTS_PER_BLOCK;  // 977
  multiinf_kernel<<<blocks, TPB, 0, stream>>>(xs, mus, alphas, wsv, out);
}

// Round 11
// 103.031 us; speedup vs baseline: 1.2521x; 1.0236x over previous
//
#include <hip/hip_runtime.h>
#include <math.h>

// Problem constants (reference: N=250000, D=16, L=6, K=64, gamma=0.1)
#define NPOINTS 250000
#define LL 6
#define DD 16
#define KK 64
#define TPB 384            // 6 waves; wave w handles layer w for the block's 256 points
#define PTS_PER_BLOCK 256
#define NTILES 16          // 16 MFMA tiles of 16 points each

// LDS layout (byte offsets into smem), phase-aliased:
//  Phase A: musc: column j of layer l at (l*64+j)*64, 24576 B
//  Phase B: sxu: point p at p*80, 20480 B; smc at SMC_OFF, 6144 B
//  swv: 6 floats at SWV_OFF (never aliased)
#define SMC_OFF 20480
#define SWV_OFF 26624
#define LDS_BYTES (SWV_OFF + 32)

typedef __attribute__((ext_vector_type(8))) short bf16x8;
typedef __attribute__((ext_vector_type(4))) float f32x4;
typedef __attribute__((ext_vector_type(2))) float f32x2;

#if __has_builtin(__builtin_amdgcn_exp2f)
#define EXP2F(x) __builtin_amdgcn_exp2f(x)
#else
#define EXP2F(x) exp2f(x)
#endif
#if __has_builtin(__builtin_amdgcn_logf)
#define LOG2F(x) __builtin_amdgcn_logf(x)
#else
#define LOG2F(x) log2f(x)
#endif

#define C_AA   (-14.426950408889634f)   // -10 * log2(e)
#define C_GLN2 (0.06931471805599453f)   // gamma * ln(2)

// Fully-fused distance->log2 term. With mu pre-scaled by -1/2, MFMA emits
// x' = -ip/2, z = (1-ip)/2 = x' + 1/2. Using asin^2 series:
//   u^2 = 5*log2e*acos(ip)^2 = z*Q(z),  Q(z)=4*SQ_C^2*(1 + z/3 + 8z^2/45 + ...)
// Re-expanded in x' basis: u^2 = W(x') = w0 + x'*V(x'), so
//   t2 = aa - u^2 = (aa - w0) + x'*Vt(x'),  Vt = -V (degree-8 Horner, 8 fma)
// w0 = u^2(x=0) = (SQ_C*pi/2)^2. Coeffs: exact binomial shift of the series.
#define W0  17.797117f
#define VT0 (-45.292974f)
#define VT1 (-28.550058f)
#define VT2 (-28.372228f)
#define VT3 (-30.774333f)
#define VT4 (-30.651245f)
#define VT5 (-24.814423f)
#define VT6 (-14.639929f)
#define VT7 (-5.4693079f)
#define VT8 (-0.96031854f)

__device__ __forceinline__ f32x2 s2(float v) { f32x2 r; r.x = v; r.y = v; return r; }

__device__ __forceinline__ ushort bf16_rne(float f) {
  unsigned u = __float_as_uint(f);
  unsigned r = u + 0x7FFFu + ((u >> 16) & 1u);
  return (ushort)(r >> 16);
}

// packed pair: exp2( (aa-w0) + xp*Vt(xp) ), xp = -ip/2 from MFMA
__device__ __forceinline__ f32x2 term2(f32x2 xp, f32x2 aaw) {
  f32x2 V = s2(VT8);
  V = __builtin_elementwise_fma(V, xp, s2(VT7));
  V = __builtin_elementwise_fma(V, xp, s2(VT6));
  V = __builtin_elementwise_fma(V, xp, s2(VT5));
  V = __builtin_elementwise_fma(V, xp, s2(VT4));
  V = __builtin_elementwise_fma(V, xp, s2(VT3));
  V = __builtin_elementwise_fma(V, xp, s2(VT2));
  V = __builtin_elementwise_fma(V, xp, s2(VT1));
  V = __builtin_elementwise_fma(V, xp, s2(VT0));
  f32x2 t2 = __builtin_elementwise_fma(xp, V, aaw);
  f32x2 e; e.x = EXP2F(t2.x); e.y = EXP2F(t2.y);
  return e;
}

__global__ __launch_bounds__(TPB, 5) void
multiinf_kernel(const float* __restrict__ xs,
                const float* __restrict__ mus,    // [L, D, K]
                const float* __restrict__ alphas, // [L, K]
                const float* __restrict__ wsv,    // [L]
                float* __restrict__ out) {
  __shared__ __align__(16) char smem[LDS_BYTES];
  float* swv = (float*)(smem + SWV_OFF);
  float* smc = (float*)(smem + SMC_OFF);

  const int tid = threadIdx.x;
  const int w = tid >> 6;            // wave = layer
  const int lane = tid & 63;
  const int c = lane & 15;           // MFMA col: point-in-tile (comp-in-cb for A read)
  const int q = lane >> 4;           // quad
  const int h = q & 1;               // dim half for B (x) reads
  const int pbase = blockIdx.x * PTS_PER_BLOCK;

  // Prefetch this thread's x point (threads 0..255) to overlap with phase A
  float xv[DD];
  {
    int gidx = pbase + tid;
    if (tid < PTS_PER_BLOCK && gidx < NPOINTS) {
      const float4* x4 = (const float4*)(xs + (size_t)gidx * DD);
#pragma unroll
      for (int j = 0; j < 4; ++j) {
        float4 a = x4[j];
        xv[j * 4 + 0] = a.x; xv[j * 4 + 1] = a.y;
        xv[j * 4 + 2] = a.z; xv[j * 4 + 3] = a.w;
      }
    } else {
#pragma unroll
      for (int d = 0; d < DD; ++d) xv[d] = 0.0f;
    }
  }

  // ---- Phase A: wave w normalizes column `lane` of layer w, scales by -1/2
  //      (exact), splits bf16 hi/lo ----
  {
    const float* colp = mus + w * (DD * KK) + lane;   // stride KK over d
    float v[DD];
    float ss = 0.0f;
#pragma unroll
    for (int d = 0; d < DD; ++d) { v[d] = colp[d * KK]; ss = fmaf(v[d], v[d], ss); }
    float inv = -0.5f / sqrtf(ss);   // normalize AND scale by -1/2 (exact scale)
    unsigned hw[8], lw[8];
#pragma unroll
    for (int i = 0; i < 8; ++i) {
      float a0 = v[2 * i] * inv;
      float a1 = v[2 * i + 1] * inv;
      ushort h0 = bf16_rne(a0), h1 = bf16_rne(a1);
      float hf0 = __uint_as_float((unsigned)h0 << 16);
      float hf1 = __uint_as_float((unsigned)h1 << 16);
      ushort l0 = bf16_rne(a0 - hf0), l1 = bf16_rne(a1 - hf1);
      hw[i] = (unsigned)h0 | ((unsigned)h1 << 16);
      lw[i] = (unsigned)l0 | ((unsigned)l1 << 16);
    }
    uint4* colq = (uint4*)(smem + (w * 64 + lane) * 64);
    colq[0] = make_uint4(hw[0], hw[1], hw[2], hw[3]);
    colq[1] = make_uint4(hw[4], hw[5], hw[6], hw[7]);
    colq[2] = make_uint4(lw[0], lw[1], lw[2], lw[3]);
    colq[3] = make_uint4(lw[4], lw[5], lw[6], lw[7]);
  }
  // per-comp constant: aa - w0 = C_AA*alpha - w0
  float av = fmaf(C_AA, alphas[w * 64 + lane], -W0);
  if (tid < LL) { float t = wsv[tid]; swv[tid] = expf(-t * t); }
  __syncthreads();

  // ---- Read A fragments (mu', loop-invariant) into registers ----
  bf16x8 Am[4];
  f32x2 aaL[4], aaH[4];   // aaw for comps q*4+{0,1} and q*4+{2,3} per cb
#pragma unroll
  for (int cb = 0; cb < 4; ++cb) {
    Am[cb] = *(const bf16x8*)(smem + (w * 64 + cb * 16 + c) * 64 + q * 16);
    int base = cb * 16 + q * 4;
    aaL[cb].x = __shfl(av, base + 0, 64);
    aaL[cb].y = __shfl(av, base + 1, 64);
    aaH[cb].x = __shfl(av, base + 2, 64);
    aaH[cb].y = __shfl(av, base + 3, 64);
  }
  __syncthreads();   // all mu reads done; musc region now reusable

  // ---- Phase B: stage x (bf16 hi/lo) into sxu ----
  if (tid < PTS_PER_BLOCK) {
    unsigned hw[8], lw[8];
#pragma unroll
    for (int i = 0; i < 8; ++i) {
      ushort h0 = bf16_rne(xv[2 * i]);
      ushort h1 = bf16_rne(xv[2 * i + 1]);
      float hf0 = __uint_as_float((unsigned)h0 << 16);
      float hf1 = __uint_as_float((unsigned)h1 << 16);
      ushort l0 = bf16_rne(xv[2 * i] - hf0);
      ushort l1 = bf16_rne(xv[2 * i + 1] - hf1);
      hw[i] = (unsigned)h0 | ((unsigned)h1 << 16);
      lw[i] = (unsigned)l0 | ((unsigned)l1 << 16);
    }
    uint4* pq = (uint4*)(smem + tid * 80);
    pq[0] = make_uint4(hw[0], hw[1], hw[2], hw[3]);
    pq[1] = make_uint4(hw[4], hw[5], hw[6], hw[7]);
    pq[2] = make_uint4(lw[0], lw[1], lw[2], lw[3]);
    pq[3] = make_uint4(lw[4], lw[5], lw[6], lw[7]);
  }
  __syncthreads();

  // ---- Main loop: 16 tiles of 16 points; lane owns point c of each tile ----
  float* smcw = smc + w * PTS_PER_BLOCK;
  bf16x8 Bh = *(const bf16x8*)(smem + (0 * 16 + c) * 80 + h * 16);
  bf16x8 Bl = *(const bf16x8*)(smem + (0 * 16 + c) * 80 + 32 + h * 16);
  for (int t = 0; t < NTILES; ++t) {
    int tn = ((t + 1) & 15) * 16 + c;
    bf16x8 Bhn = *(const bf16x8*)(smem + tn * 80 + h * 16);
    bf16x8 Bln = *(const bf16x8*)(smem + tn * 80 + 32 + h * 16);

    f32x2 S01 = s2(0.0f), S23 = s2(0.0f);
#pragma unroll
    for (int cb = 0; cb < 4; ++cb) {
      f32x4 acc = {0.0f, 0.0f, 0.0f, 0.0f};
      acc = __builtin_amdgcn_mfma_f32_16x16x32_bf16(Am[cb], Bh, acc, 0, 0, 0);
      acc = __builtin_amdgcn_mfma_f32_16x16x32_bf16(Am[cb], Bl, acc, 0, 0, 0);
      f32x2 a01; a01.x = acc[0]; a01.y = acc[1];
      f32x2 a23; a23.x = acc[2]; a23.y = acc[3];
      S01 += term2(a01, aaL[cb]);
      S23 += term2(a23, aaH[cb]);
    }
    f32x2 Sf = S01 + S23;
    float St = Sf.x + Sf.y;
    St += __shfl_xor(St, 16, 64);
    St += __shfl_xor(St, 32, 64);

    if (lane < 16) smcw[t * 16 + c] = St;   // raw sum; log applied in epilogue
    Bh = Bhn;
    Bl = Bln;
  }
  __syncthreads();

  // ---- Epilogue: recurrence + smooth-min, one thread per point ----
  if (tid < PTS_PER_BLOCK) {
    float F = 0.0f;
#pragma unroll
    for (int l = 0; l < LL; ++l) {
      float wv = swv[l];
      float mc = C_GLN2 * LOG2F(smc[l * PTS_PER_BLOCK + tid]);  // gamma*ln(S)
      F = fmaf(wv, fmaxf(F, 0.0f), (1.0f - wv) * mc);
    }
    int idx = pbase + tid;
    if (idx < NPOINTS) {
      float e = EXP2F(F * C_AA);              // exp(-F/0.1)
      out[idx] = C_GLN2 * LOG2F(1.0f + e);    // 0.1 * ln(1 + e)
    }
  }
}

extern "C" void kernel_launch(void* const* d_in, const int* in_sizes, int n_in,
                              void* d_out, int out_size, void* d_ws, size_t ws_size,
                              hipStream_t stream) {
  const float* xs = (const float*)d_in[0];     // [N, D]
  const float* mus = (const float*)d_in[1];    // [L, D, K]
  const float* alphas = (const float*)d_in[2]; // [L, K]
  const float* wsv = (const float*)d_in[3];    // [L]
  float* out = (float*)d_out;
  (void)d_ws; (void)ws_size;

  const int blocks = (NPOINTS + PTS_PER_BLOCK - 1) / PTS_PER_BLOCK;  // 977
  multiinf_kernel<<<blocks, TPB, 0, stream>>>(xs, mus, alphas, wsv, out);
}

// Round 12
// 100.195 us; speedup vs baseline: 1.2876x; 1.0283x over previous
//
#include <hip/hip_runtime.h>
#include <math.h>

// Problem constants (reference: N=250000, D=16, L=6, K=64, gamma=0.1)
#define NPOINTS 250000
#define LL 6
#define DD 16
#define KK 64
#define TPB 384            // 6 waves; wave w handles layer w for the block's 256 points
#define PTS_PER_BLOCK 256
#define NTILES 16          // 16 MFMA tiles of 16 points each

// LDS layout (byte offsets into smem), phase-aliased:
//  Phase A: musc: column j of layer l at (l*64+j)*64, 24576 B
//  Phase B: sxu: point p at p*80, 20480 B; smc at SMC_OFF, 6144 B
//  swv: 6 floats at SWV_OFF (never aliased)
#define SMC_OFF 20480
#define SWV_OFF 26624
#define LDS_BYTES (SWV_OFF + 32)

typedef __attribute__((ext_vector_type(8))) short bf16x8;
typedef __attribute__((ext_vector_type(4))) float f32x4;
typedef __attribute__((ext_vector_type(2))) float f32x2;

#if __has_builtin(__builtin_amdgcn_exp2f)
#define EXP2F(x) __builtin_amdgcn_exp2f(x)
#else
#define EXP2F(x) exp2f(x)
#endif
#if __has_builtin(__builtin_amdgcn_logf)
#define LOG2F(x) __builtin_amdgcn_logf(x)
#else
#define LOG2F(x) log2f(x)
#endif

#define C_AA   (-14.426950408889634f)   // -10 * log2(e)
#define C_GLN2 (0.06931471805599453f)   // gamma * ln(2)

// Fused distance->log2 term (see R10/R11): with mu pre-scaled by -1/2, MFMA
// emits x' = -ip/2 and t2 = (aa - w0) + x'*Vt(x'), u^2 = w0 - x'*Vt(x').
// Vt was the degree-8 Taylor-shift; here economized to DEGREE 6 via exact
// Chebyshev identities on t=2x' in [-1,1]:
//   t^8 -> 2t^6 - 1.25t^4 + 0.25t^2 - 1/128   (error T8/128)
//   t^7 -> 1.75t^5 - 0.875t^3 + 0.109375t     (error T7/64)
// cumulative |err| <= |c8|/128 + |c7|/64 ~= 7e-4 in t2 (log2 units).
// Endpoint check: u^2(ip=1) = -3.2e-4 ~= 0. 
#define W0  17.797117f
#define VT0 (-45.292945f)
#define VT1 (-28.559404f)
#define VT2 (-28.375979f)
#define VT3 (-30.475230f)
#define VT4 (-30.576219f)
#define VT5 (-27.207285f)
#define VT6 (-15.120090f)

__device__ __forceinline__ f32x2 s2(float v) { f32x2 r; r.x = v; r.y = v; return r; }

__device__ __forceinline__ ushort bf16_rne(float f) {
  unsigned u = __float_as_uint(f);
  unsigned r = u + 0x7FFFu + ((u >> 16) & 1u);
  return (ushort)(r >> 16);
}

// packed pair: exp2( (aa-w0) + xp*Vt(xp) ), xp = -ip/2 from MFMA
__device__ __forceinline__ f32x2 term2(f32x2 xp, f32x2 aaw) {
  f32x2 V = s2(VT6);
  V = __builtin_elementwise_fma(V, xp, s2(VT5));
  V = __builtin_elementwise_fma(V, xp, s2(VT4));
  V = __builtin_elementwise_fma(V, xp, s2(VT3));
  V = __builtin_elementwise_fma(V, xp, s2(VT2));
  V = __builtin_elementwise_fma(V, xp, s2(VT1));
  V = __builtin_elementwise_fma(V, xp, s2(VT0));
  f32x2 t2 = __builtin_elementwise_fma(xp, V, aaw);
  f32x2 e; e.x = EXP2F(t2.x); e.y = EXP2F(t2.y);
  return e;
}

__global__ __launch_bounds__(TPB, 5) void
multiinf_kernel(const float* __restrict__ xs,
                const float* __restrict__ mus,    // [L, D, K]
                const float* __restrict__ alphas, // [L, K]
                const float* __restrict__ wsv,    // [L]
                float* __restrict__ out) {
  __shared__ __align__(16) char smem[LDS_BYTES];
  float* swv = (float*)(smem + SWV_OFF);
  float* smc = (float*)(smem + SMC_OFF);

  const int tid = threadIdx.x;
  const int w = tid >> 6;            // wave = layer
  const int lane = tid & 63;
  const int c = lane & 15;           // MFMA col: point-in-tile (comp-in-cb for A read)
  const int q = lane >> 4;           // quad
  const int h = q & 1;               // dim half for B (x) reads
  const int pbase = blockIdx.x * PTS_PER_BLOCK;

  // Prefetch this thread's x point (threads 0..255) to overlap with phase A
  float xv[DD];
  {
    int gidx = pbase + tid;
    if (tid < PTS_PER_BLOCK && gidx < NPOINTS) {
      const float4* x4 = (const float4*)(xs + (size_t)gidx * DD);
#pragma unroll
      for (int j = 0; j < 4; ++j) {
        float4 a = x4[j];
        xv[j * 4 + 0] = a.x; xv[j * 4 + 1] = a.y;
        xv[j * 4 + 2] = a.z; xv[j * 4 + 3] = a.w;
      }
    } else {
#pragma unroll
      for (int d = 0; d < DD; ++d) xv[d] = 0.0f;
    }
  }

  // ---- Phase A: wave w normalizes column `lane` of layer w, scales by -1/2
  //      (exact), splits bf16 hi/lo ----
  {
    const float* colp = mus + w * (DD * KK) + lane;   // stride KK over d
    float v[DD];
    float ss = 0.0f;
#pragma unroll
    for (int d = 0; d < DD; ++d) { v[d] = colp[d * KK]; ss = fmaf(v[d], v[d], ss); }
    float inv = -0.5f / sqrtf(ss);   // normalize AND scale by -1/2 (exact scale)
    unsigned hw[8], lw[8];
#pragma unroll
    for (int i = 0; i < 8; ++i) {
      float a0 = v[2 * i] * inv;
      float a1 = v[2 * i + 1] * inv;
      ushort h0 = bf16_rne(a0), h1 = bf16_rne(a1);
      float hf0 = __uint_as_float((unsigned)h0 << 16);
      float hf1 = __uint_as_float((unsigned)h1 << 16);
      ushort l0 = bf16_rne(a0 - hf0), l1 = bf16_rne(a1 - hf1);
      hw[i] = (unsigned)h0 | ((unsigned)h1 << 16);
      lw[i] = (unsigned)l0 | ((unsigned)l1 << 16);
    }
    uint4* colq = (uint4*)(smem + (w * 64 + lane) * 64);
    colq[0] = make_uint4(hw[0], hw[1], hw[2], hw[3]);
    colq[1] = make_uint4(hw[4], hw[5], hw[6], hw[7]);
    colq[2] = make_uint4(lw[0], lw[1], lw[2], lw[3]);
    colq[3] = make_uint4(lw[4], lw[5], lw[6], lw[7]);
  }
  // per-comp constant: aa - w0 = C_AA*alpha - w0
  float av = fmaf(C_AA, alphas[w * 64 + lane], -W0);
  if (tid < LL) { float t = wsv[tid]; swv[tid] = expf(-t * t); }
  __syncthreads();

  // ---- Read A fragments (mu', loop-invariant) into registers ----
  bf16x8 Am[4];
  f32x2 aaL[4], aaH[4];   // aaw for comps q*4+{0,1} and q*4+{2,3} per cb
#pragma unroll
  for (int cb = 0; cb < 4; ++cb) {
    Am[cb] = *(const bf16x8*)(smem + (w * 64 + cb * 16 + c) * 64 + q * 16);
    int base = cb * 16 + q * 4;
    aaL[cb].x = __shfl(av, base + 0, 64);
    aaL[cb].y = __shfl(av, base + 1, 64);
    aaH[cb].x = __shfl(av, base + 2, 64);
    aaH[cb].y = __shfl(av, base + 3, 64);
  }
  __syncthreads();   // all mu reads done; musc region now reusable

  // ---- Phase B: stage x (bf16 hi/lo) into sxu ----
  if (tid < PTS_PER_BLOCK) {
    unsigned hw[8], lw[8];
#pragma unroll
    for (int i = 0; i < 8; ++i) {
      ushort h0 = bf16_rne(xv[2 * i]);
      ushort h1 = bf16_rne(xv[2 * i + 1]);
      float hf0 = __uint_as_float((unsigned)h0 << 16);
      float hf1 = __uint_as_float((unsigned)h1 << 16);
      ushort l0 = bf16_rne(xv[2 * i] - hf0);
      ushort l1 = bf16_rne(xv[2 * i + 1] - hf1);
      hw[i] = (unsigned)h0 | ((unsigned)h1 << 16);
      lw[i] = (unsigned)l0 | ((unsigned)l1 << 16);
    }
    uint4* pq = (uint4*)(smem + tid * 80);
    pq[0] = make_uint4(hw[0], hw[1], hw[2], hw[3]);
    pq[1] = make_uint4(hw[4], hw[5], hw[6], hw[7]);
    pq[2] = make_uint4(lw[0], lw[1], lw[2], lw[3]);
    pq[3] = make_uint4(lw[4], lw[5], lw[6], lw[7]);
  }
  __syncthreads();

  // ---- Main loop: 16 tiles of 16 points; lane owns point c of each tile ----
  float* smcw = smc + w * PTS_PER_BLOCK;
  bf16x8 Bh = *(const bf16x8*)(smem + (0 * 16 + c) * 80 + h * 16);
  bf16x8 Bl = *(const bf16x8*)(smem + (0 * 16 + c) * 80 + 32 + h * 16);
  for (int t = 0; t < NTILES; ++t) {
    int tn = ((t + 1) & 15) * 16 + c;
    bf16x8 Bhn = *(const bf16x8*)(smem + tn * 80 + h * 16);
    bf16x8 Bln = *(const bf16x8*)(smem + tn * 80 + 32 + h * 16);

    f32x2 S01 = s2(0.0f), S23 = s2(0.0f);
#pragma unroll
    for (int cb = 0; cb < 4; ++cb) {
      f32x4 acc = {0.0f, 0.0f, 0.0f, 0.0f};
      acc = __builtin_amdgcn_mfma_f32_16x16x32_bf16(Am[cb], Bh, acc, 0, 0, 0);
      acc = __builtin_amdgcn_mfma_f32_16x16x32_bf16(Am[cb], Bl, acc, 0, 0, 0);
      f32x2 a01; a01.x = acc[0]; a01.y = acc[1];
      f32x2 a23; a23.x = acc[2]; a23.y = acc[3];
      S01 += term2(a01, aaL[cb]);
      S23 += term2(a23, aaH[cb]);
    }
    f32x2 Sf = S01 + S23;
    float St = Sf.x + Sf.y;
    St += __shfl_xor(St, 16, 64);
    St += __shfl_xor(St, 32, 64);

    if (lane < 16) smcw[t * 16 + c] = St;   // raw sum; log applied in epilogue
    Bh = Bhn;
    Bl = Bln;
  }
  __syncthreads();

  // ---- Epilogue: recurrence + smooth-min, one thread per point ----
  if (tid < PTS_PER_BLOCK) {
    float F = 0.0f;
#pragma unroll
    for (int l = 0; l < LL; ++l) {
      float wv = swv[l];
      float mc = C_GLN2 * LOG2F(smc[l * PTS_PER_BLOCK + tid]);  // gamma*ln(S)
      F = fmaf(wv, fmaxf(F, 0.0f), (1.0f - wv) * mc);
    }
    int idx = pbase + tid;
    if (idx < NPOINTS) {
      float e = EXP2F(F * C_AA);              // exp(-F/0.1)
      out[idx] = C_GLN2 * LOG2F(1.0f + e);    // 0.1 * ln(1 + e)
    }
  }
}

extern "C" void kernel_launch(void* const* d_in, const int* in_sizes, int n_in,
                              void* d_out, int out_size, void* d_ws, size_t ws_size,
                              hipStream_t stream) {
  const float* xs = (const float*)d_in[0];     // [N, D]
  const float* mus = (const float*)d_in[1];    // [L, D, K]
  const float* alphas = (const float*)d_in[2]; // [L, K]
  const float* wsv = (const float*)d_in[3];    // [L]
  float* out = (float*)d_out;
  (void)d_ws; (void)ws_size;

  const int blocks = (NPOINTS + PTS_PER_BLOCK - 1) / PTS_PER_BLOCK;  // 977
  multiinf_kernel<<<blocks, TPB, 0, stream>>>(xs, mus, alphas, wsv, out);
}

// Round 13
// 97.704 us; speedup vs baseline: 1.3204x; 1.0255x over previous
//
#include <hip/hip_runtime.h>
#include <math.h>

// Problem constants (reference: N=250000, D=16, L=6, K=64, gamma=0.1)
#define NPOINTS 250000
#define LL 6
#define DD 16
#define KK 64
#define TPB 384            // 6 waves; wave w handles layer w for the block's 256 points
#define PTS_PER_BLOCK 256
#define NTILES 16          // 16 MFMA tiles of 16 points each

// LDS layout (byte offsets into smem), phase-aliased:
//  Phase A: musc: column j of layer l at (l*64+j)*64, 24576 B
//  Phase B: sxu: point p at p*80, 20480 B; smc at SMC_OFF, 6144 B
//  swv: 6 floats at SWV_OFF (never aliased)
#define SMC_OFF 20480
#define SWV_OFF 26624
#define LDS_BYTES (SWV_OFF + 32)

typedef __attribute__((ext_vector_type(8))) short bf16x8;
typedef __attribute__((ext_vector_type(4))) float f32x4;
typedef __attribute__((ext_vector_type(2))) float f32x2;

#if __has_builtin(__builtin_amdgcn_exp2f)
#define EXP2F(x) __builtin_amdgcn_exp2f(x)
#else
#define EXP2F(x) exp2f(x)
#endif
#if __has_builtin(__builtin_amdgcn_logf)
#define LOG2F(x) __builtin_amdgcn_logf(x)
#else
#define LOG2F(x) log2f(x)
#endif

#define C_AA   (-14.426950408889634f)   // -10 * log2(e)
#define C_GLN2 (0.06931471805599453f)   // gamma * ln(2)

// Fused distance->log2 term (R10-R12): with mu pre-scaled by -1/2, MFMA emits
// x' = -ip/2 and t2 = (aa - w0) + x'*Vt(x'), u^2 = w0 - x'*Vt(x').
// Vt: degree-8 Taylor-shift economized R12 to degree 6 (T8/T7), now to
// DEGREE 5 via exact t^6 = 1.5t^4 - 0.5625t^2 + 0.03125 + T6/32 (t = 2x'),
// dropping T6/32: |err(V)| <= |c6|/32 = 7.4e-3, x'-weighted => |err(t2)| <=
// 3.7e-3 log2 => <=2.6e-4 in F. Endpoint: u^2(ip=1) = +3.4e-3 log2 (~0).
#define W0  17.797117f
#define VT0 (-45.300328f)
#define VT1 (-28.559404f)
#define VT2 (-27.844414f)
#define VT3 (-30.475230f)
#define VT4 (-36.246253f)
#define VT5 (-27.207285f)

__device__ __forceinline__ f32x2 s2(float v) { f32x2 r; r.x = v; r.y = v; return r; }

__device__ __forceinline__ ushort bf16_rne(float f) {
  unsigned u = __float_as_uint(f);
  unsigned r = u + 0x7FFFu + ((u >> 16) & 1u);
  return (ushort)(r >> 16);
}

// packed pair: exp2( (aa-w0) + xp*Vt(xp) ), xp = -ip/2 from MFMA
__device__ __forceinline__ f32x2 term2(f32x2 xp, f32x2 aaw) {
  f32x2 V = s2(VT5);
  V = __builtin_elementwise_fma(V, xp, s2(VT4));
  V = __builtin_elementwise_fma(V, xp, s2(VT3));
  V = __builtin_elementwise_fma(V, xp, s2(VT2));
  V = __builtin_elementwise_fma(V, xp, s2(VT1));
  V = __builtin_elementwise_fma(V, xp, s2(VT0));
  f32x2 t2 = __builtin_elementwise_fma(xp, V, aaw);
  f32x2 e; e.x = EXP2F(t2.x); e.y = EXP2F(t2.y);
  return e;
}

__global__ __launch_bounds__(TPB, 5) void
multiinf_kernel(const float* __restrict__ xs,
                const float* __restrict__ mus,    // [L, D, K]
                const float* __restrict__ alphas, // [L, K]
                const float* __restrict__ wsv,    // [L]
                float* __restrict__ out) {
  __shared__ __align__(16) char smem[LDS_BYTES];
  float* swv = (float*)(smem + SWV_OFF);
  float* smc = (float*)(smem + SMC_OFF);

  const int tid = threadIdx.x;
  const int w = tid >> 6;            // wave = layer
  const int lane = tid & 63;
  const int c = lane & 15;           // MFMA col: point-in-tile (comp-in-cb for A read)
  const int q = lane >> 4;           // quad
  const int h = q & 1;               // dim half for B (x) reads
  const int pbase = blockIdx.x * PTS_PER_BLOCK;

  // Prefetch this thread's x point (threads 0..255) to overlap with phase A
  float xv[DD];
  {
    int gidx = pbase + tid;
    if (tid < PTS_PER_BLOCK && gidx < NPOINTS) {
      const float4* x4 = (const float4*)(xs + (size_t)gidx * DD);
#pragma unroll
      for (int j = 0; j < 4; ++j) {
        float4 a = x4[j];
        xv[j * 4 + 0] = a.x; xv[j * 4 + 1] = a.y;
        xv[j * 4 + 2] = a.z; xv[j * 4 + 3] = a.w;
      }
    } else {
#pragma unroll
      for (int d = 0; d < DD; ++d) xv[d] = 0.0f;
    }
  }

  // ---- Phase A: wave w normalizes column `lane` of layer w, scales by -1/2
  //      (exact), splits bf16 hi/lo ----
  {
    const float* colp = mus + w * (DD * KK) + lane;   // stride KK over d
    float v[DD];
    float ss = 0.0f;
#pragma unroll
    for (int d = 0; d < DD; ++d) { v[d] = colp[d * KK]; ss = fmaf(v[d], v[d], ss); }
    float inv = -0.5f / sqrtf(ss);   // normalize AND scale by -1/2 (exact scale)
    unsigned hw[8], lw[8];
#pragma unroll
    for (int i = 0; i < 8; ++i) {
      float a0 = v[2 * i] * inv;
      float a1 = v[2 * i + 1] * inv;
      ushort h0 = bf16_rne(a0), h1 = bf16_rne(a1);
      float hf0 = __uint_as_float((unsigned)h0 << 16);
      float hf1 = __uint_as_float((unsigned)h1 << 16);
      ushort l0 = bf16_rne(a0 - hf0), l1 = bf16_rne(a1 - hf1);
      hw[i] = (unsigned)h0 | ((unsigned)h1 << 16);
      lw[i] = (unsigned)l0 | ((unsigned)l1 << 16);
    }
    uint4* colq = (uint4*)(smem + (w * 64 + lane) * 64);
    colq[0] = make_uint4(hw[0], hw[1], hw[2], hw[3]);
    colq[1] = make_uint4(hw[4], hw[5], hw[6], hw[7]);
    colq[2] = make_uint4(lw[0], lw[1], lw[2], lw[3]);
    colq[3] = make_uint4(lw[4], lw[5], lw[6], lw[7]);
  }
  // per-comp constant: aa - w0 = C_AA*alpha - w0
  float av = fmaf(C_AA, alphas[w * 64 + lane], -W0);
  if (tid < LL) { float t = wsv[tid]; swv[tid] = expf(-t * t); }
  __syncthreads();

  // ---- Read A fragments (mu', loop-invariant) into registers ----
  bf16x8 Am[4];
  f32x2 aaL[4], aaH[4];   // aaw for comps q*4+{0,1} and q*4+{2,3} per cb
#pragma unroll
  for (int cb = 0; cb < 4; ++cb) {
    Am[cb] = *(const bf16x8*)(smem + (w * 64 + cb * 16 + c) * 64 + q * 16);
    int base = cb * 16 + q * 4;
    aaL[cb].x = __shfl(av, base + 0, 64);
    aaL[cb].y = __shfl(av, base + 1, 64);
    aaH[cb].x = __shfl(av, base + 2, 64);
    aaH[cb].y = __shfl(av, base + 3, 64);
  }
  __syncthreads();   // all mu reads done; musc region now reusable

  // ---- Phase B: stage x (bf16 hi/lo) into sxu ----
  if (tid < PTS_PER_BLOCK) {
    unsigned hw[8], lw[8];
#pragma unroll
    for (int i = 0; i < 8; ++i) {
      ushort h0 = bf16_rne(xv[2 * i]);
      ushort h1 = bf16_rne(xv[2 * i + 1]);
      float hf0 = __uint_as_float((unsigned)h0 << 16);
      float hf1 = __uint_as_float((unsigned)h1 << 16);
      ushort l0 = bf16_rne(xv[2 * i] - hf0);
      ushort l1 = bf16_rne(xv[2 * i + 1] - hf1);
      hw[i] = (unsigned)h0 | ((unsigned)h1 << 16);
      lw[i] = (unsigned)l0 | ((unsigned)l1 << 16);
    }
    uint4* pq = (uint4*)(smem + tid * 80);
    pq[0] = make_uint4(hw[0], hw[1], hw[2], hw[3]);
    pq[1] = make_uint4(hw[4], hw[5], hw[6], hw[7]);
    pq[2] = make_uint4(lw[0], lw[1], lw[2], lw[3]);
    pq[3] = make_uint4(lw[4], lw[5], lw[6], lw[7]);
  }
  __syncthreads();

  // ---- Main loop: 16 tiles of 16 points; lane owns point c of each tile ----
  float* smcw = smc + w * PTS_PER_BLOCK;
  bf16x8 Bh = *(const bf16x8*)(smem + (0 * 16 + c) * 80 + h * 16);
  bf16x8 Bl = *(const bf16x8*)(smem + (0 * 16 + c) * 80 + 32 + h * 16);
  for (int t = 0; t < NTILES; ++t) {
    int tn = ((t + 1) & 15) * 16 + c;
    bf16x8 Bhn = *(const bf16x8*)(smem + tn * 80 + h * 16);
    bf16x8 Bln = *(const bf16x8*)(smem + tn * 80 + 32 + h * 16);

    f32x2 S01 = s2(0.0f), S23 = s2(0.0f);
#pragma unroll
    for (int cb = 0; cb < 4; ++cb) {
      f32x4 acc = {0.0f, 0.0f, 0.0f, 0.0f};
      acc = __builtin_amdgcn_mfma_f32_16x16x32_bf16(Am[cb], Bh, acc, 0, 0, 0);
      acc = __builtin_amdgcn_mfma_f32_16x16x32_bf16(Am[cb], Bl, acc, 0, 0, 0);
      f32x2 a01; a01.x = acc[0]; a01.y = acc[1];
      f32x2 a23; a23.x = acc[2]; a23.y = acc[3];
      S01 += term2(a01, aaL[cb]);
      S23 += term2(a23, aaH[cb]);
    }
    f32x2 Sf = S01 + S23;
    float St = Sf.x + Sf.y;
    St += __shfl_xor(St, 16, 64);
    St += __shfl_xor(St, 32, 64);

    if (lane < 16) smcw[t * 16 + c] = St;   // raw sum; log applied in epilogue
    Bh = Bhn;
    Bl = Bln;
  }
  __syncthreads();

  // ---- Epilogue: recurrence + smooth-min, one thread per point ----
  if (tid < PTS_PER_BLOCK) {
    float F = 0.0f;
#pragma unroll
    for (int l = 0; l < LL; ++l) {
      float wv = swv[l];
      float mc = C_GLN2 * LOG2F(smc[l * PTS_PER_BLOCK + tid]);  // gamma*ln(S)
      F = fmaf(wv, fmaxf(F, 0.0f), (1.0f - wv) * mc);
    }
    int idx = pbase + tid;
    if (idx < NPOINTS) {
      float e = EXP2F(F * C_AA);              // exp(-F/0.1)
      out[idx] = C_GLN2 * LOG2F(1.0f + e);    // 0.1 * ln(1 + e)
    }
  }
}

extern "C" void kernel_launch(void* const* d_in, const int* in_sizes, int n_in,
                              void* d_out, int out_size, void* d_ws, size_t ws_size,
                              hipStream_t stream) {
  const float* xs = (const float*)d_in[0];     // [N, D]
  const float* mus = (const float*)d_in[1];    // [L, D, K]
  const float* alphas = (const float*)d_in[2]; // [L, K]
  const float* wsv = (const float*)d_in[3];    // [L]
  float* out = (float*)d_out;
  (void)d_ws; (void)ws_size;

  const int blocks = (NPOINTS + PTS_PER_BLOCK - 1) / PTS_PER_BLOCK;  // 977
  multiinf_kernel<<<blocks, TPB, 0, stream>>>(xs, mus, alphas, wsv, out);
}